// Round 3
// baseline (119.085 us; speedup 1.0000x reference)
//
#include <hip/hip_runtime.h>

#define BLK  256   // threads per block
#define IT   8     // i-values per thread (register blocking)
#define JS   64    // j-splits -> grid = 8 x 64 = 512 blocks (2/CU)
#define TILE 256   // j-tile staged in LDS (== BLK)

// Fused: partial risk-set sums (register-blocked 8x over i) accumulated with
// device-scope float atomics into sumacc[i]; last-arriving block computes the
// per-i contributions and the final scalar loss. acc/sumacc pre-zeroed by a
// hipMemsetAsync node on the stream.
__global__ void cox_fused(const float* __restrict__ risk,
                          const float* __restrict__ tm,
                          const float* __restrict__ event,
                          float* __restrict__ sumacc,  // [n]  pre-zeroed
                          float* __restrict__ acc,     // [4]: counter in acc[0]
                          float* __restrict__ out,
                          int n, int jch, int nblocks) {
    __shared__ float st[TILE];
    __shared__ float se[TILE];
    __shared__ bool  s_last;
    const int tid = threadIdx.x;
    const int i0  = blockIdx.x * (BLK * IT);
    const int j0  = blockIdx.y * jch;

    float ti[IT], sum[IT];
    #pragma unroll
    for (int r = 0; r < IT; ++r) {
        ti[r]  = tm[i0 + r * BLK + tid];   // coalesced
        sum[r] = 0.f;
    }

    for (int jb = 0; jb < jch; jb += TILE) {
        const int j = j0 + jb + tid;
        st[tid] = tm[j];
        se[tid] = __expf(risk[j]);
        __syncthreads();
        const float4* st4 = (const float4*)st;
        const float4* se4 = (const float4*)se;
        #pragma unroll 4
        for (int k4 = 0; k4 < TILE / 4; ++k4) {
            const float4 t4 = st4[k4];   // ds_read_b128 broadcast: conflict-free
            const float4 e4 = se4[k4];
            #pragma unroll
            for (int r = 0; r < IT; ++r) {
                sum[r] += (t4.x >= ti[r]) ? e4.x : 0.f;
                sum[r] += (t4.y >= ti[r]) ? e4.y : 0.f;
                sum[r] += (t4.z >= ti[r]) ? e4.z : 0.f;
                sum[r] += (t4.w >= ti[r]) ? e4.w : 0.f;
            }
        }
        __syncthreads();
    }

    // Cross-block j-combine: device-scope float atomics (order nondeterminism
    // ~1e-5 abs, threshold 0.185).
    #pragma unroll
    for (int r = 0; r < IT; ++r)
        atomicAdd(&sumacc[i0 + r * BLK + tid], sum[r]);

    __threadfence();   // release our sumacc adds before arrival
    if (tid == 0) {
        const unsigned old = atomicAdd((unsigned*)&acc[0], 1u);
        s_last = (old == (unsigned)(nblocks - 1));
    }
    __syncthreads();
    if (!s_last) return;
    __threadfence();   // acquire: observe all other blocks' adds

    // Last block finalizes: 64 KB of sums, 64 logs/thread.
    float num = 0.f, den = 0.f;
    for (int i = tid; i < n; i += BLK) {
        const float s  = __hip_atomic_load(&sumacc[i], __ATOMIC_RELAXED,
                                           __HIP_MEMORY_SCOPE_AGENT); // bypass L1
        const float ev = event[i];
        num += (risk[i] - logf(s)) * ev;
        den += ev;
    }
    #pragma unroll
    for (int off = 32; off > 0; off >>= 1) {
        num += __shfl_down(num, off);
        den += __shfl_down(den, off);
    }
    __shared__ float sn[BLK / 64], sd[BLK / 64];
    const int wave = tid >> 6;
    if ((tid & 63) == 0) { sn[wave] = num; sd[wave] = den; }
    __syncthreads();
    if (tid == 0) {
        float tn = 0.f, td = 0.f;
        #pragma unroll
        for (int w = 0; w < BLK / 64; ++w) { tn += sn[w]; td += sd[w]; }
        out[0] = -tn / td;
    }
}

extern "C" void kernel_launch(void* const* d_in, const int* in_sizes, int n_in,
                              void* d_out, int out_size, void* d_ws, size_t ws_size,
                              hipStream_t stream) {
    const float* risk  = (const float*)d_in[0];
    const float* tm    = (const float*)d_in[1];
    const float* event = (const float*)d_in[2];
    float* out = (float*)d_out;
    const int n = in_sizes[0];           // 16384

    float* sumacc = (float*)d_ws;        // [n]
    float* acc    = sumacc + n;          // [4]

    // Zero sums + arrival counter (graph-capturable memset node, 64 KB).
    hipMemsetAsync(sumacc, 0, (size_t)(n + 4) * sizeof(float), stream);

    const int nib = n / (BLK * IT);      // 8 i-blocks
    const int jch = n / JS;              // 256
    dim3 g(nib, JS);
    cox_fused<<<g, BLK, 0, stream>>>(risk, tm, event, sumacc, acc, out,
                                     n, jch, nib * JS);
}

// Round 4
// 83.717 us; speedup vs baseline: 1.4225x; 1.4225x over previous
//
#include <hip/hip_runtime.h>

#define NB   4096   // time-buckets (uniform [0,1) -> ~4 elems/bucket)
#define BLK  256
#define SCT  1024   // scan-kernel threads

__device__ __forceinline__ int bucketof(float t) {
    int b = (int)(t * (float)NB);
    if (b < 0) b = 0;
    if (b > NB - 1) b = NB - 1;
    return b;   // monotone in t; equal t -> equal b  (matches >= semantics)
}

// K1: e_j = exp(risk_j); per-bucket count and exp-sum (global atomics, ~4/bucket).
__global__ void cox_hist(const float* __restrict__ risk,
                         const float* __restrict__ tm,
                         float* __restrict__ evec,
                         int* __restrict__ count,
                         float* __restrict__ bsum) {
    const int j = blockIdx.x * BLK + threadIdx.x;
    const float t = tm[j];
    const float e = __expf(risk[j]);
    evec[j] = e;
    const int b = bucketof(t);
    atomicAdd(&count[b], 1);
    atomicAdd(&bsum[b], e);
}

// K2: off[b] = exclusive prefix of count; suf[b] = exclusive suffix of bsum.
// Single block, Hillis-Steele over NB=4096 (counts <= 2^24: exact in fp32).
__global__ void cox_scan(const int* __restrict__ count,
                         const float* __restrict__ bsum,
                         int* __restrict__ off,
                         float* __restrict__ suf) {
    __shared__ float p0[NB], p1[NB];
    const int tid = threadIdx.x;
    float *src = p0, *dst = p1;

    for (int b = tid; b < NB; b += SCT) src[b] = (float)count[b];
    __syncthreads();
    for (int s = 1; s < NB; s <<= 1) {
        for (int b = tid; b < NB; b += SCT)
            dst[b] = src[b] + ((b >= s) ? src[b - s] : 0.f);
        __syncthreads();
        float* tswap = src; src = dst; dst = tswap;
    }
    for (int b = tid; b < NB; b += SCT) off[b] = (int)src[b] - count[b];
    __syncthreads();

    for (int b = tid; b < NB; b += SCT) src[b] = bsum[b];
    __syncthreads();
    for (int s = 1; s < NB; s <<= 1) {
        for (int b = tid; b < NB; b += SCT)
            dst[b] = src[b] + ((b + s < NB) ? src[b + s] : 0.f);
        __syncthreads();
        float* tswap = src; src = dst; dst = tswap;
    }
    for (int b = tid; b < NB; b += SCT) suf[b] = src[b] - bsum[b];
}

// K3: counting-sort scatter of (t, e) by bucket. After this, off[b] = bucket end.
__global__ void cox_scatter(const float* __restrict__ tm,
                            const float* __restrict__ evec,
                            int* __restrict__ off,
                            float* __restrict__ sortedT,
                            float* __restrict__ sortedE) {
    const int j = blockIdx.x * BLK + threadIdx.x;
    const float t = tm[j];
    const int b = bucketof(t);
    const int pos = atomicAdd(&off[b], 1);
    sortedT[pos] = t;
    sortedE[pos] = evec[j];
}

// K4: per-i within-bucket correction + log, block reduce, counter finalize.
__global__ void cox_eval(const float* __restrict__ risk,
                         const float* __restrict__ tm,
                         const float* __restrict__ event,
                         const int* __restrict__ count,
                         const int* __restrict__ off,
                         const float* __restrict__ suf,
                         const float* __restrict__ sortedT,
                         const float* __restrict__ sortedE,
                         float* __restrict__ acc,   // [0]=num,[1]=den,[2]=counter
                         float* __restrict__ out,
                         int nblocks) {
    __shared__ bool s_last;
    const int tid = threadIdx.x;
    const int i = blockIdx.x * BLK + tid;
    const float t = tm[i];
    const int b = bucketof(t);
    const int end = off[b];            // post-scatter: end of bucket
    const int start = end - count[b];
    float corr = 0.f;
    for (int k = start; k < end; ++k)
        corr += (sortedT[k] >= t) ? sortedE[k] : 0.f;   // includes k==i (t>=t)
    const float ev = event[i];
    float num = (risk[i] - logf(suf[b] + corr)) * ev;
    float den = ev;
    #pragma unroll
    for (int o = 32; o > 0; o >>= 1) {
        num += __shfl_down(num, o);
        den += __shfl_down(den, o);
    }
    __shared__ float sn[BLK / 64], sd[BLK / 64];
    const int wave = tid >> 6;
    if ((tid & 63) == 0) { sn[wave] = num; sd[wave] = den; }
    __syncthreads();
    if (tid == 0) {
        float tn = 0.f, td = 0.f;
        #pragma unroll
        for (int w = 0; w < BLK / 64; ++w) { tn += sn[w]; td += sd[w]; }
        atomicAdd(&acc[0], tn);
        atomicAdd(&acc[1], td);
        __threadfence();
        const unsigned old = atomicAdd(&((unsigned*)acc)[2], 1u);
        s_last = (old == (unsigned)(nblocks - 1));
    }
    __syncthreads();
    if (s_last && tid == 0) {
        const float fn = atomicAdd(&acc[0], 0.f);
        const float fd = atomicAdd(&acc[1], 0.f);
        out[0] = -fn / fd;
    }
}

extern "C" void kernel_launch(void* const* d_in, const int* in_sizes, int n_in,
                              void* d_out, int out_size, void* d_ws, size_t ws_size,
                              hipStream_t stream) {
    const float* risk  = (const float*)d_in[0];
    const float* tm    = (const float*)d_in[1];
    const float* event = (const float*)d_in[2];
    float* out = (float*)d_out;
    const int n = in_sizes[0];           // 16384

    // ws layout
    float* evec    = (float*)d_ws;           // n
    float* sortedT = evec + n;               // n
    float* sortedE = sortedT + n;            // n
    int*   count   = (int*)(sortedE + n);    // NB   (zeroed)
    float* bsum    = (float*)(count + NB);   // NB   (zeroed)
    float* acc     = bsum + NB;              // 4    (zeroed)
    int*   off     = (int*)(acc + 4);        // NB
    float* suf     = (float*)(off + NB);     // NB

    // Zero count + bsum + acc in one contiguous memset node (32 KB + 16 B).
    hipMemsetAsync(count, 0, (size_t)NB * 8 + 16, stream);

    const int nb = n / BLK;                  // 64
    cox_hist   <<<nb, BLK, 0, stream>>>(risk, tm, evec, count, bsum);
    cox_scan   <<<1, SCT, 0, stream>>>(count, bsum, off, suf);
    cox_scatter<<<nb, BLK, 0, stream>>>(tm, evec, off, sortedT, sortedE);
    cox_eval   <<<nb, BLK, 0, stream>>>(risk, tm, event, count, off, suf,
                                        sortedT, sortedE, acc, out, nb);
}